// Round 2
// baseline (749.410 us; speedup 1.0000x reference)
//
#include <hip/hip_runtime.h>
#include <hip/hip_bf16.h>
#include <cmath>

typedef __bf16 bf16_t;
typedef bf16_t bf16x8 __attribute__((ext_vector_type(8)));
typedef float floatx4 __attribute__((ext_vector_type(4)));

#define NFEAT 26
#define DIM 64
#define DENSE_IN 13
#define CARD 100000
#define HBOT 8
#define KSTEPS 54   // (26*64 + 64) / 32 K-steps of the top-MLP first GEMM

// ---------------- prep kernels (write fragments into d_ws) ----------------

// Build bf16 B-fragments of tw1 [1728+64? no: 1728 x 16] in MFMA lane order.
// slot = t*64 + lane; lane holds B[k = t*32 + (lane>>4)*8 + j][n = lane&15].
__global__ __launch_bounds__(256) void prep_b(const float* __restrict__ tw1,
                                              bf16_t* __restrict__ ws_b) {
    int slot = blockIdx.x * 256 + threadIdx.x;
    if (slot >= KSTEPS * 64) return;
    int t  = slot >> 6;
    int l  = slot & 63;
    int n  = l & 15;
    int k0 = t * 32 + (l >> 4) * 8;
    bf16x8 v;
    #pragma unroll
    for (int j = 0; j < 8; ++j)
        v[j] = (bf16_t)tw1[(k0 + j) * 16 + n];
    *(bf16x8*)(ws_b + slot * 8) = v;
}

// Bottom MLP for every sample; output 64 bf16 per sample in natural order
// (natural order == A-fragment dwordx4 order for the dense K-steps).
__global__ __launch_bounds__(256) void prep_dense(
    const float* __restrict__ dense_x,
    const float* __restrict__ w1, const float* __restrict__ b1,
    const float* __restrict__ w2, const float* __restrict__ b2,
    bf16_t* __restrict__ ws_d) {
    int s = blockIdx.x * 256 + threadIdx.x;   // 0..16383
    float x[DENSE_IN];
    #pragma unroll
    for (int i = 0; i < DENSE_IN; ++i) x[i] = dense_x[s * DENSE_IN + i];
    float h8[HBOT];
    #pragma unroll
    for (int j = 0; j < HBOT; ++j) {
        float acc = b1[j];
        #pragma unroll
        for (int i = 0; i < DENSE_IN; ++i) acc = fmaf(x[i], w1[i * HBOT + j], acc);
        h8[j] = fmaxf(acc, 0.f);
    }
    #pragma unroll
    for (int c = 0; c < 8; ++c) {
        bf16x8 v;
        #pragma unroll
        for (int jj = 0; jj < 8; ++jj) {
            int d = c * 8 + jj;
            float acc = b2[d];
            #pragma unroll
            for (int j = 0; j < HBOT; ++j) acc = fmaf(h8[j], w2[j * DIM + d], acc);
            v[jj] = (bf16_t)acc;
        }
        *(bf16x8*)(ws_d + s * DIM + c * 8) = v;
    }
}

// ---------------- main fused gather + top-MLP kernel ----------------
// 512 blocks x 256 threads. Block = 32 samples = 2 tiles of 16.
// wave = tile*? : tile = wave&1, half = wave>>1 (features 0..12 / 13..25).
__global__ __launch_bounds__(256) void dlrm_main(
    const int* __restrict__ sparse_x,
    const float* __restrict__ tables,
    const bf16_t* __restrict__ ws_b,
    const bf16_t* __restrict__ ws_d,
    const float* __restrict__ tb1,
    const float* __restrict__ tw2,
    const float* __restrict__ tb2,
    float* __restrict__ out) {
    __shared__ float partial[2][64][4];   // 2 KB combine buffer

    const int block = blockIdx.x;
    const int tid   = threadIdx.x;
    const int lane  = tid & 63;
    const int wave  = tid >> 6;
    const int tile  = wave & 1;
    const int half  = wave >> 1;
    const int m     = lane & 15;
    const int q     = lane >> 4;
    const int sample = block * 32 + tile * 16 + m;

    // per-lane index fetch (one-time, 52 B per lane)
    int idxs[13];
    {
        const int* myidx = sparse_x + sample * NFEAT + half * 13;
        #pragma unroll
        for (int i = 0; i < 13; ++i) idxs[i] = myidx[i];
    }

    floatx4 acc = {0.f, 0.f, 0.f, 0.f};

    #pragma unroll 4
    for (int ff = 0; ff < 13; ++ff) {
        const int f = half * 13 + ff;
        const float* row = tables + ((long)f * CARD + idxs[ff]) * DIM;
        #pragma unroll
        for (int h = 0; h < 2; ++h) {
            const float4 p0 = *(const float4*)(row + h * 32 + q * 8);
            const float4 p1 = *(const float4*)(row + h * 32 + q * 8 + 4);
            bf16x8 a;
            a[0] = (bf16_t)p0.x; a[1] = (bf16_t)p0.y;
            a[2] = (bf16_t)p0.z; a[3] = (bf16_t)p0.w;
            a[4] = (bf16_t)p1.x; a[5] = (bf16_t)p1.y;
            a[6] = (bf16_t)p1.z; a[7] = (bf16_t)p1.w;
            bf16x8 b = *(const bf16x8*)(ws_b + ((f * 2 + h) * 64 + lane) * 8);
            acc = __builtin_amdgcn_mfma_f32_16x16x32_bf16(a, b, acc, 0, 0, 0);
        }
    }

    if (half == 0) {
        // dense K-steps (t = 52, 53); A from prebuilt per-sample dense bf16
        #pragma unroll
        for (int tp = 0; tp < 2; ++tp) {
            bf16x8 a = *(const bf16x8*)(ws_d + sample * DIM + tp * 32 + q * 8);
            bf16x8 b = *(const bf16x8*)(ws_b + ((52 + tp) * 64 + lane) * 8);
            acc = __builtin_amdgcn_mfma_f32_16x16x32_bf16(a, b, acc, 0, 0, 0);
        }
    } else {
        #pragma unroll
        for (int i = 0; i < 4; ++i) partial[tile][lane][i] = acc[i];
    }
    __syncthreads();

    if (half == 0) {
        #pragma unroll
        for (int i = 0; i < 4; ++i) acc[i] += partial[tile][lane][i];

        // epilogue: +tb1, relu, x tw2, reduce over 16 hidden, +tb2, sigmoid
        const int h = lane & 15;            // hidden unit (C/D col)
        const float bias = tb1[h];
        const float wout = tw2[h];
        float p[4];
        #pragma unroll
        for (int i = 0; i < 4; ++i) p[i] = fmaxf(acc[i] + bias, 0.f) * wout;
        #pragma unroll
        for (int off = 1; off < 16; off <<= 1) {
            #pragma unroll
            for (int i = 0; i < 4; ++i) p[i] += __shfl_xor(p[i], off, 64);
        }
        if (h == 0) {
            const float bout = tb2[0];
            #pragma unroll
            for (int i = 0; i < 4; ++i) {
                float logit = p[i] + bout;
                out[block * 32 + tile * 16 + q * 4 + i] = 1.f / (1.f + expf(-logit));
            }
        }
    }
}

extern "C" void kernel_launch(void* const* d_in, const int* in_sizes, int n_in,
                              void* d_out, int out_size, void* d_ws, size_t ws_size,
                              hipStream_t stream) {
    const float* dense_x  = (const float*)d_in[0];
    const int*   sparse_x = (const int*)d_in[1];
    const float* tables   = (const float*)d_in[2];
    const float* w1  = (const float*)d_in[3];
    const float* b1  = (const float*)d_in[4];
    const float* w2  = (const float*)d_in[5];
    const float* b2  = (const float*)d_in[6];
    const float* tw1 = (const float*)d_in[7];
    const float* tb1 = (const float*)d_in[8];
    const float* tw2 = (const float*)d_in[9];
    const float* tb2 = (const float*)d_in[10];
    float* out = (float*)d_out;

    bf16_t* ws_b = (bf16_t*)d_ws;                         // 54*64*8*2 = 55296 B
    bf16_t* ws_d = (bf16_t*)((char*)d_ws + 65536);        // 16384*64*2 = 2 MB

    prep_b<<<(KSTEPS * 64 + 255) / 256, 256, 0, stream>>>(tw1, ws_b);
    prep_dense<<<16384 / 256, 256, 0, stream>>>(dense_x, w1, b1, w2, b2, ws_d);
    dlrm_main<<<512, 256, 0, stream>>>(sparse_x, tables, ws_b, ws_d,
                                       tb1, tw2, tb2, out);
}